// Round 1
// 367.906 us; speedup vs baseline: 1.0897x; 1.0897x over previous
//
#include <hip/hip_runtime.h>
#include <hip/hip_bf16.h>
#include <math.h>

// Problem constants (B=2,S=1024 -> T=2048; D=1024; H=4096; E=8; top-2)
// ALL inputs/outputs are FLOAT32. We convert x/W1/W2/Ws1/Ws2 to bf16 in the
// workspace for MFMA; biases and gating stay f32.
#define NTOK 2048
#define DDIM 1024
#define HDIM 4096
#define NEXP 8
#define NROWS (3 * NTOK)  // 2*NTOK routed + NTOK shared rows in grouped space
#define KSPLIT2 2         // split-K factor for GEMM2 (4->2: longer K-loops, half the atomics)

typedef __bf16 bf16x8 __attribute__((ext_vector_type(8)));
typedef float f32x4 __attribute__((ext_vector_type(4)));
typedef __attribute__((address_space(1))) char as1_char;
typedef __attribute__((address_space(3))) char as3_char;

__device__ __forceinline__ void async16(const void* g, void* l) {
  // async global->LDS, 16B/lane; LDS dest = wave-uniform base + lane*16
  __builtin_amdgcn_global_load_lds((as1_char*)g, (as3_char*)l, 16, 0, 0);
}

// Branch-free erf (Abramowitz-Stegun 7.1.26, |err|<=1.5e-7) -> exact-form gelu.
__device__ __forceinline__ float gelu_fast(float v) {
  const float x = v * 0.70710678118654752f;
  const float ax = fabsf(x);
  const float t = __builtin_amdgcn_rcpf(1.0f + 0.3275911f * ax);
  float p = 1.061405429f;
  p = p * t - 1.453152027f;
  p = p * t + 1.421413741f;
  p = p * t - 0.284496736f;
  p = p * t + 0.254829592f;
  const float y = 1.0f - p * t * __expf(-ax * ax);
  const float erfv = copysignf(y, x);
  return 0.5f * v * (1.0f + erfv);
}

// ---------------------------------------------------------------------------
// f32 -> bf16 conversion, 8 elems/thread, 16B vector store. n % 2048 == 0.
// ---------------------------------------------------------------------------
__global__ void __launch_bounds__(256) cvt_bf16(const float* __restrict__ in,
                                                __hip_bfloat16* __restrict__ out) {
  const size_t i = ((size_t)blockIdx.x * 256 + threadIdx.x) * 8;
  const float4 a = *(const float4*)(in + i);
  const float4 b = *(const float4*)(in + i + 4);
  union { __hip_bfloat16 h[8]; uint4 u; } p;
  p.h[0] = __float2bfloat16(a.x); p.h[1] = __float2bfloat16(a.y);
  p.h[2] = __float2bfloat16(a.z); p.h[3] = __float2bfloat16(a.w);
  p.h[4] = __float2bfloat16(b.x); p.h[5] = __float2bfloat16(b.y);
  p.h[6] = __float2bfloat16(b.z); p.h[7] = __float2bfloat16(b.w);
  *(uint4*)(out + i) = p.u;
}

__global__ void moe_zero_out(float* __restrict__ a) {
  a[(size_t)blockIdx.x * 256 + threadIdx.x] = 0.f;
}
__global__ void moe_zero_misc(int* counts) {
  if (threadIdx.x < NEXP) counts[threadIdx.x] = 0;
}

// ---------------------------------------------------------------------------
// Core 128x128 tile GEMM, TRIPLE-BUFFERED, depth-2 prefetch (round-5):
// rocprof showed the depth-1 double-buffer is still latency-bound
// (MfmaUtil 13%, HBM 27%, occupancy 27%): the vmcnt(4) waits on loads issued
// only ~1 iter (~250 cyc) earlier vs ~900 cyc HBM latency. With 3 LDS buffers
// the wave waits (vmcnt(8)) on loads issued TWO iterations earlier.
// A [M x K] rows K-contiguous bf16, B^T [N x K] rows K-contiguous bf16.
// 256 threads = 4 waves (2x2), per-wave 64x64 as 4x4 frags of 16x16x32 MFMA.
// LDS: 3 buffers x (A 8KB | B 8KB) = 48KB, unpadded (global_load_lds layout).
// 48KB -> 3 blocks/CU (12 waves/CU = 37.5% cap, above the measured 27%).
// Correctness of the raw-barrier schedule: stage(i+2) overwrites buf
// (i+2)%3 == (i-1)%3, whose readers all passed the trailing barrier of
// iter i-1 (their ds_reads were consumed by MFMA before that barrier); the
// per-wave vmcnt(8) before the leading barrier guarantees each wave's OWN
// stage(i) DMAs have landed, and the barrier publishes them to all waves.
// ---------------------------------------------------------------------------
__device__ __forceinline__ void gemm_core(const char* ga0, const char* ga1,
                                          const char* gb0, const char* gb1,
                                          char* sm, int Kbytes, int tid,
                                          f32x4 acc[4][4]) {
  const int w = tid >> 6, l = tid & 63;
  const int lr = l & 15, quad = l >> 4;
  const int wr = w >> 1, wc = w & 1;
  const int aoff = (wr * 64 + lr) * 64 + quad * 16;
  const int boff = 8192 + (wc * 64 + lr) * 64 + quad * 16;
  const int niter = Kbytes >> 6;

  auto stage = [&](int it, int buf) {
    char* base = sm + buf * 16384 + w * 1024;
    const int kb = it * 64;
    async16(ga0 + kb, base);
    async16(ga1 + kb, base + 4096);
    async16(gb0 + kb, base + 8192);
    async16(gb1 + kb, base + 12288);
  };

  stage(0, 0);
  stage(1, 1);
  int cur = 0, nxt = 2;
  for (int i = 0; i < niter; ++i) {
    if (i + 2 < niter) {
      stage(i + 2, nxt);                      // 12 DMAs now outstanding (own)
      __builtin_amdgcn_s_waitcnt(0x0F78);     // vmcnt(8): wait stage(i) only
    } else if (i + 1 < niter) {
      __builtin_amdgcn_s_waitcnt(0x0F74);     // vmcnt(4): stage(i+1) in flight
    } else {
      __builtin_amdgcn_s_waitcnt(0x0F70);     // vmcnt(0): last tile
    }
    __builtin_amdgcn_s_barrier();             // raw: no vmcnt(0) drain of prefetch
    const char* rb = sm + cur * 16384;
    bf16x8 av[4], bv[4];
#pragma unroll
    for (int i2 = 0; i2 < 4; ++i2) av[i2] = *(const bf16x8*)(rb + aoff + i2 * 1024);
#pragma unroll
    for (int j = 0; j < 4; ++j) bv[j] = *(const bf16x8*)(rb + boff + j * 1024);
#pragma unroll
    for (int i2 = 0; i2 < 4; ++i2)
#pragma unroll
      for (int j = 0; j < 4; ++j)
        acc[i2][j] = __builtin_amdgcn_mfma_f32_16x16x32_bf16(av[i2], bv[j], acc[i2][j], 0, 0, 0);
    __builtin_amdgcn_s_barrier();             // all reads of buf[cur] done before
    cur = (cur == 2) ? 0 : cur + 1;           // next iter's stage overwrites it
    nxt = (nxt == 2) ? 0 : nxt + 1;
  }
}

// ---------------------------------------------------------------------------
// Gating: one wave per token, all f32. scores = sigmoid(x @ Wg^T + bg + bias);
// top-2 with lax.top_k tie-break (lowest index first). Slot via atomics.
// ---------------------------------------------------------------------------
__global__ void __launch_bounds__(64) moe_gate(
    const float* __restrict__ x, const float* __restrict__ Wg,
    const float* __restrict__ bg, const float* __restrict__ bias,
    int* __restrict__ counts, int* __restrict__ topk_idx,
    float* __restrict__ topk_w, int* __restrict__ slot) {
  const int t = blockIdx.x, lane = threadIdx.x;
  float xv[16];
#pragma unroll
  for (int q = 0; q < 16; ++q) xv[q] = x[(size_t)t * DDIM + q * 64 + lane];
  float sc[NEXP];
#pragma unroll
  for (int e = 0; e < NEXP; ++e) {
    float s = 0.f;
#pragma unroll
    for (int q = 0; q < 16; ++q) s += xv[q] * Wg[(size_t)e * DDIM + q * 64 + lane];
#pragma unroll
    for (int o = 32; o > 0; o >>= 1) s += __shfl_xor(s, o, 64);
    sc[e] = 1.0f / (1.0f + expf(-(s + bg[e] + bias[e])));
  }
  if (lane == 0) {
    int k0 = 0;
    for (int e = 1; e < NEXP; ++e)
      if (sc[e] > sc[k0]) k0 = e;
    int k1 = (k0 == 0) ? 1 : 0;
    for (int e = 0; e < NEXP; ++e) {
      if (e == k0) continue;
      if (sc[e] > sc[k1]) k1 = e;
    }
    topk_idx[t * 2 + 0] = k0;
    topk_idx[t * 2 + 1] = k1;
    topk_w[t * 2 + 0] = sc[k0];
    topk_w[t * 2 + 1] = sc[k1];
    slot[t * 2 + 0] = atomicAdd(&counts[k0], 1);
    slot[t * 2 + 1] = atomicAdd(&counts[k1], 1);
  }
}

__global__ void moe_scan(const int* __restrict__ counts, int* __restrict__ offsets) {
  if (threadIdx.x == 0) {
    int s = 0;
    for (int e = 0; e < NEXP; ++e) { offsets[e] = s; s += counts[e]; }
    offsets[NEXP] = s;  // == 2*NTOK
  }
}

__global__ void moe_scatter(const int* __restrict__ topk_idx, const float* __restrict__ topk_w,
                            const int* __restrict__ slot, const int* __restrict__ offsets,
                            int* __restrict__ row_token, float* __restrict__ row_w) {
  const int t = blockIdx.x * blockDim.x + threadIdx.x;
  if (t >= NTOK) return;
#pragma unroll
  for (int k = 0; k < 2; ++k) {
    const int e = topk_idx[t * 2 + k];
    const int rg = offsets[e] + slot[t * 2 + k];
    row_token[rg] = t;
    row_w[rg] = topk_w[t * 2 + k];
  }
  // shared "expert 8": every token, weight 1.0, rows [2*NTOK, 3*NTOK)
  row_token[2 * NTOK + t] = t;
  row_w[2 * NTOK + t] = 1.0f;
}

// ---------------------------------------------------------------------------
// Grouped GEMM1: h1[row,:] = gelu(xbf[token(row),:] @ W1bf[e]^T + b1[e]) (bf16)
// grid (H/128, 16, E+1); e==NEXP -> shared expert (Ws1bf, bs1).
// ---------------------------------------------------------------------------
__global__ void __launch_bounds__(256) moe_gemm1(
    const __hip_bfloat16* __restrict__ xbf, const __hip_bfloat16* __restrict__ W1bf,
    const float* __restrict__ b1, const __hip_bfloat16* __restrict__ Ws1bf,
    const float* __restrict__ bs1, const int* __restrict__ counts,
    const int* __restrict__ offsets, const int* __restrict__ row_token,
    __hip_bfloat16* __restrict__ h1) {
  __shared__ alignas(16) char sm[49152];
  const int e = blockIdx.z, mt = blockIdx.y, nt = blockIdx.x;
  const int cnt = (e < NEXP) ? counts[e] : NTOK;
  if (mt * 128 >= cnt) return;
  const int off = (e < NEXP) ? offsets[e] : 2 * NTOK;
  const __hip_bfloat16* Bw = (e < NEXP) ? (W1bf + (size_t)e * HDIM * DDIM) : Ws1bf;
  const float* bb = (e < NEXP) ? (b1 + e * HDIM) : bs1;

  const int tid = threadIdx.x;
  const int w = tid >> 6, l = tid & 63;
  const int mrow = w * 16 + (l >> 2);  // 0..63 staging row
  const int colb = (l & 3) * 16;       // 16B chunk col offset

  const int r0 = mt * 128 + mrow, r1 = r0 + 64;
  const int c0 = (r0 < cnt) ? r0 : (cnt - 1);
  const int c1 = (r1 < cnt) ? r1 : (cnt - 1);
  const int t0 = row_token[off + c0];
  const int t1 = row_token[off + c1];
  const char* ga0 = (const char*)xbf + (size_t)t0 * (DDIM * 2) + colb;
  const char* ga1 = (const char*)xbf + (size_t)t1 * (DDIM * 2) + colb;
  const char* gb0 = (const char*)Bw + (size_t)(nt * 128 + mrow) * (DDIM * 2) + colb;
  const char* gb1 = (const char*)Bw + (size_t)(nt * 128 + mrow + 64) * (DDIM * 2) + colb;

  f32x4 acc[4][4] = {};
  gemm_core(ga0, ga1, gb0, gb1, sm, DDIM * 2, tid, acc);

  const int lr = l & 15, quad = l >> 4, wr = w >> 1, wc = w & 1;
#pragma unroll
  for (int i = 0; i < 4; ++i) {
#pragma unroll
    for (int r = 0; r < 4; ++r) {
      const int rowe = mt * 128 + wr * 64 + i * 16 + quad * 4 + r;
      if (rowe >= cnt) continue;  // don't stomp next expert's rows
      const size_t orow = (size_t)(off + rowe) * HDIM;
#pragma unroll
      for (int j = 0; j < 4; ++j) {
        const int h = nt * 128 + wc * 64 + j * 16 + lr;
        const float v = acc[i][j][r] + bb[h];
        h1[orow + h] = __float2bfloat16(gelu_fast(v));
      }
    }
  }
}

// ---------------------------------------------------------------------------
// Grouped GEMM2 with split-K: out[token,:] += w(row)*(h1[row,:] @ W2bf[e]^T)
// (+ w*b2[e] from K-chunk 0 only). grid x = KSPLIT2 * (D/128); y = m-tiles;
// z = E+1 groups. out is f32, pre-zeroed; f32 atomicAdd accumulates.
// ---------------------------------------------------------------------------
__global__ void __launch_bounds__(256) moe_gemm2(
    const __hip_bfloat16* __restrict__ h1, const __hip_bfloat16* __restrict__ W2bf,
    const float* __restrict__ b2, const __hip_bfloat16* __restrict__ Ws2bf,
    const float* __restrict__ bs2, const int* __restrict__ counts,
    const int* __restrict__ offsets, const int* __restrict__ row_token,
    const float* __restrict__ row_w, float* __restrict__ out) {
  __shared__ alignas(16) char sm[49152];
  const int e = blockIdx.z, mt = blockIdx.y;
  const int nt = blockIdx.x & (DDIM / 128 - 1);
  const int kc = blockIdx.x >> 3;  // K-chunk 0..KSPLIT2-1
  const int cnt = (e < NEXP) ? counts[e] : NTOK;
  if (mt * 128 >= cnt) return;
  const int off = (e < NEXP) ? offsets[e] : 2 * NTOK;
  const __hip_bfloat16* Bw = (e < NEXP) ? (W2bf + (size_t)e * DDIM * HDIM) : Ws2bf;
  const float* bb = (e < NEXP) ? (b2 + e * DDIM) : bs2;

  const int tid = threadIdx.x;
  const int w = tid >> 6, l = tid & 63;
  const int mrow = w * 16 + (l >> 2);
  const int colb = (l & 3) * 16;
  const int KB = (HDIM * 2) / KSPLIT2;       // bytes of K per chunk
  const size_t kofs = (size_t)kc * KB;       // byte offset into the K dim

  // A rows contiguous in grouped h1; rows >= cnt read the next group's valid
  // (finite) data and are discarded at the store guard.
  const char* ga0 = (const char*)h1 + (size_t)(off + mt * 128 + mrow) * (HDIM * 2) + kofs + colb;
  const char* ga1 = (const char*)h1 + (size_t)(off + mt * 128 + mrow + 64) * (HDIM * 2) + kofs + colb;
  const char* gb0 = (const char*)Bw + (size_t)(nt * 128 + mrow) * (HDIM * 2) + kofs + colb;
  const char* gb1 = (const char*)Bw + (size_t)(nt * 128 + mrow + 64) * (HDIM * 2) + kofs + colb;

  f32x4 acc[4][4] = {};
  gemm_core(ga0, ga1, gb0, gb1, sm, KB, tid, acc);

  const int lr = l & 15, quad = l >> 4, wr = w >> 1, wc = w & 1;
#pragma unroll
  for (int i = 0; i < 4; ++i) {
#pragma unroll
    for (int r = 0; r < 4; ++r) {
      const int rowe = mt * 128 + wr * 64 + i * 16 + quad * 4 + r;
      if (rowe >= cnt) continue;
      const int rg = off + rowe;
      const int tok = row_token[rg];
      const float wt = row_w[rg];
#pragma unroll
      for (int j = 0; j < 4; ++j) {
        const int d = nt * 128 + wc * 64 + j * 16 + lr;
        const float base = (kc == 0) ? bb[d] : 0.f;  // bias once per output
        atomicAdd(&out[(size_t)tok * DDIM + d], wt * (acc[i][j][r] + base));
      }
    }
  }
}

// ---------------------------------------------------------------------------
extern "C" void kernel_launch(void* const* d_in, const int* in_sizes, int n_in,
                              void* d_out, int out_size, void* d_ws, size_t ws_size,
                              hipStream_t stream) {
  (void)in_sizes; (void)n_in; (void)out_size; (void)ws_size;
  const float* x    = (const float*)d_in[0];
  const float* Wg   = (const float*)d_in[1];
  const float* bg   = (const float*)d_in[2];
  const float* bias = (const float*)d_in[3];
  const float* W1   = (const float*)d_in[4];
  const float* b1   = (const float*)d_in[5];
  const float* W2   = (const float*)d_in[6];
  const float* b2   = (const float*)d_in[7];
  const float* Ws1  = (const float*)d_in[8];
  const float* bs1  = (const float*)d_in[9];
  const float* Ws2  = (const float*)d_in[10];
  const float* bs2  = (const float*)d_in[11];
  float* out = (float*)d_out;

  // workspace carve-out (~200 MB)
  char* ws = (char*)d_ws;
  size_t cur = 0;
  auto take = [&](size_t b) -> void* {
    void* p = ws + cur;
    cur += (b + 255) & ~(size_t)255;
    return p;
  };
  int* counts    = (int*)take(NEXP * 4);
  int* offsets   = (int*)take((NEXP + 1) * 4);
  int* topk_idx  = (int*)take(NTOK * 2 * 4);
  float* topk_w  = (float*)take(NTOK * 2 * 4);
  int* slot      = (int*)take(NTOK * 2 * 4);
  int* row_token = (int*)take(NROWS * 4);
  float* row_w   = (float*)take(NROWS * 4);
  __hip_bfloat16* xbf   = (__hip_bfloat16*)take((size_t)NTOK * DDIM * 2);        //  4 MB
  __hip_bfloat16* W1bf  = (__hip_bfloat16*)take((size_t)NEXP * HDIM * DDIM * 2); // 67 MB
  __hip_bfloat16* W2bf  = (__hip_bfloat16*)take((size_t)NEXP * DDIM * HDIM * 2); // 67 MB
  __hip_bfloat16* Ws1bf = (__hip_bfloat16*)take((size_t)HDIM * DDIM * 2);        //  8 MB
  __hip_bfloat16* Ws2bf = (__hip_bfloat16*)take((size_t)DDIM * HDIM * 2);        //  8 MB
  __hip_bfloat16* h1    = (__hip_bfloat16*)take((size_t)(NROWS + 64) * HDIM * 2);// 51 MB

  // f32 -> bf16 conversions (all sizes divisible by 2048)
  cvt_bf16<<<(NTOK * DDIM) / 2048, 256, 0, stream>>>(x, xbf);
  cvt_bf16<<<(NEXP * HDIM * DDIM) / 2048, 256, 0, stream>>>(W1, W1bf);
  cvt_bf16<<<(NEXP * DDIM * HDIM) / 2048, 256, 0, stream>>>(W2, W2bf);
  cvt_bf16<<<(HDIM * DDIM) / 2048, 256, 0, stream>>>(Ws1, Ws1bf);
  cvt_bf16<<<(DDIM * HDIM) / 2048, 256, 0, stream>>>(Ws2, Ws2bf);

  moe_zero_misc<<<1, 64, 0, stream>>>(counts);
  moe_zero_out<<<(NTOK * DDIM) / 256, 256, 0, stream>>>(out);
  moe_gate<<<NTOK, 64, 0, stream>>>(x, Wg, bg, bias, counts, topk_idx, topk_w, slot);
  moe_scan<<<1, 1, 0, stream>>>(counts, offsets);
  moe_scatter<<<NTOK / 256, 256, 0, stream>>>(topk_idx, topk_w, slot, offsets, row_token, row_w);

  dim3 g1(HDIM / 128, NTOK / 128, NEXP + 1);  // (32, 16, 9), early-exit past counts
  moe_gemm1<<<g1, 256, 0, stream>>>(xbf, W1bf, b1, Ws1bf, bs1, counts, offsets, row_token, h1);

  dim3 g2(KSPLIT2 * (DDIM / 128), NTOK / 128, NEXP + 1);  // (16, 16, 9), split-K
  moe_gemm2<<<g2, 256, 0, stream>>>(h1, W2bf, b2, Ws2bf, bs2, counts, offsets, row_token, row_w, out);
}

// Round 2
// 365.777 us; speedup vs baseline: 1.0961x; 1.0058x over previous
//
#include <hip/hip_runtime.h>
#include <hip/hip_bf16.h>
#include <math.h>

// Problem constants (B=2,S=1024 -> T=2048; D=1024; H=4096; E=8; top-2)
// ALL inputs/outputs are FLOAT32. We convert x/W1/W2/Ws1/Ws2 to bf16 in the
// workspace for MFMA; biases and gating stay f32.
#define NTOK 2048
#define DDIM 1024
#define HDIM 4096
#define NEXP 8
#define NROWS (3 * NTOK)  // 2*NTOK routed + NTOK shared rows in grouped space
#define KSPLIT2 2         // split-K factor for GEMM2

typedef __bf16 bf16x8 __attribute__((ext_vector_type(8)));
typedef float f32x4 __attribute__((ext_vector_type(4)));
typedef __attribute__((address_space(1))) char as1_char;
typedef __attribute__((address_space(3))) char as3_char;

__device__ __forceinline__ void async16(const void* g, void* l) {
  // async global->LDS, 16B/lane; LDS dest = wave-uniform base + lane*16
  __builtin_amdgcn_global_load_lds((as1_char*)g, (as3_char*)l, 16, 0, 0);
}

// Branch-free erf (Abramowitz-Stegun 7.1.26, |err|<=1.5e-7) -> exact-form gelu.
__device__ __forceinline__ float gelu_fast(float v) {
  const float x = v * 0.70710678118654752f;
  const float ax = fabsf(x);
  const float t = __builtin_amdgcn_rcpf(1.0f + 0.3275911f * ax);
  float p = 1.061405429f;
  p = p * t - 1.453152027f;
  p = p * t + 1.421413741f;
  p = p * t - 0.284496736f;
  p = p * t + 0.254829592f;
  const float y = 1.0f - p * t * __expf(-ax * ax);
  const float erfv = copysignf(y, x);
  return 0.5f * v * (1.0f + erfv);
}

// ---------------------------------------------------------------------------
// f32 -> bf16 conversion, 8 elems/thread, 16B vector store. n % 2048 == 0.
// ---------------------------------------------------------------------------
__global__ void __launch_bounds__(256) cvt_bf16(const float* __restrict__ in,
                                                __hip_bfloat16* __restrict__ out) {
  const size_t i = ((size_t)blockIdx.x * 256 + threadIdx.x) * 8;
  const float4 a = *(const float4*)(in + i);
  const float4 b = *(const float4*)(in + i + 4);
  union { __hip_bfloat16 h[8]; uint4 u; } p;
  p.h[0] = __float2bfloat16(a.x); p.h[1] = __float2bfloat16(a.y);
  p.h[2] = __float2bfloat16(a.z); p.h[3] = __float2bfloat16(a.w);
  p.h[4] = __float2bfloat16(b.x); p.h[5] = __float2bfloat16(b.y);
  p.h[6] = __float2bfloat16(b.z); p.h[7] = __float2bfloat16(b.w);
  *(uint4*)(out + i) = p.u;
}

__global__ void moe_zero_out(float* __restrict__ a) {
  a[(size_t)blockIdx.x * 256 + threadIdx.x] = 0.f;
}
__global__ void moe_zero_misc(int* counts) {
  if (threadIdx.x < NEXP) counts[threadIdx.x] = 0;
}

// ---------------------------------------------------------------------------
// Core 128x128 tile GEMM, TRIPLE-BUFFERED, depth-2 prefetch + XOR-SWIZZLED
// LDS (round-6). Round-5 rocprof: SQ_LDS_BANK_CONFLICT = 6.68M (identical
// across rounds -> structural): with [row][64B] tiles the b128 fragment read
// puts 8 of each 16 lanes on one 4-bank group (bank-group = (lr*4+quad)&7,
// lr*4&7 in {0,4}) -> 8-way phase conflict ~2.94x. LDS pipe (~750 cyc of
// bank time per block-iter, shared per CU) was the critical path (measured
// ~1790 cyc/block-iter at 2.3 blocks/CU).
// Fix (both-sides swizzle, since global_load_lds writes linearly):
//   store: 16B chunk c of row r lands in slot c ^ ((r>>1)&3) -- achieved by
//          permuting the per-lane GLOBAL source chunk (same 64B line, no
//          coalescing loss); LDS dest stays linear lane*16.
//   read:  slot = quad ^ ((lr>>1)&3): phase bank-groups become
//          {0,4,1,5,2,6,3,7} x2 = 2 words/bank = wave64 minimum (free).
// A [M x K] rows K-contiguous bf16, B^T [N x K] rows K-contiguous bf16.
// 256 threads = 4 waves (2x2), per-wave 64x64 as 4x4 frags of 16x16x32 MFMA.
// LDS: 3 buffers x (A 8KB | B 8KB) = 48KB -> 3 blocks/CU cap.
// Schedule correctness: stage(i+2) overwrites buf (i-1)%3 whose readers all
// passed the trailing barrier of iter i-1; vmcnt(8) before the leading
// barrier guarantees stage(i)'s DMAs landed; the barrier publishes them.
// ---------------------------------------------------------------------------
__device__ __forceinline__ void gemm_core(const char* ga0, const char* ga1,
                                          const char* gb0, const char* gb1,
                                          char* sm, int Kbytes, int tid,
                                          f32x4 acc[4][4]) {
  const int w = tid >> 6, l = tid & 63;
  const int lr = l & 15, quad = l >> 4;
  const int wr = w >> 1, wc = w & 1;
  const int swz = (lr >> 1) & 3;  // row-derived slot XOR (rows == lr mod 16)
  const int aoff = (wr * 64 + lr) * 64 + ((quad ^ swz) * 16);
  const int boff = 8192 + (wc * 64 + lr) * 64 + ((quad ^ swz) * 16);
  const int niter = Kbytes >> 6;

  auto stage = [&](int it, int buf) {
    char* base = sm + buf * 16384 + w * 1024;
    const int kb = it * 64;
    async16(ga0 + kb, base);
    async16(ga1 + kb, base + 4096);
    async16(gb0 + kb, base + 8192);
    async16(gb1 + kb, base + 12288);
  };

  stage(0, 0);
  stage(1, 1);
  int cur = 0, nxt = 2;
  for (int i = 0; i < niter; ++i) {
    if (i + 2 < niter) {
      stage(i + 2, nxt);                      // 12 DMAs now outstanding (own)
      __builtin_amdgcn_s_waitcnt(0x0F78);     // vmcnt(8): wait stage(i) only
    } else if (i + 1 < niter) {
      __builtin_amdgcn_s_waitcnt(0x0F74);     // vmcnt(4): stage(i+1) in flight
    } else {
      __builtin_amdgcn_s_waitcnt(0x0F70);     // vmcnt(0): last tile
    }
    __builtin_amdgcn_s_barrier();             // raw: no vmcnt(0) drain of prefetch
    const char* rb = sm + cur * 16384;
    bf16x8 av[4], bv[4];
#pragma unroll
    for (int i2 = 0; i2 < 4; ++i2) av[i2] = *(const bf16x8*)(rb + aoff + i2 * 1024);
#pragma unroll
    for (int j = 0; j < 4; ++j) bv[j] = *(const bf16x8*)(rb + boff + j * 1024);
#pragma unroll
    for (int i2 = 0; i2 < 4; ++i2)
#pragma unroll
      for (int j = 0; j < 4; ++j)
        acc[i2][j] = __builtin_amdgcn_mfma_f32_16x16x32_bf16(av[i2], bv[j], acc[i2][j], 0, 0, 0);
    __builtin_amdgcn_s_barrier();             // all reads of buf[cur] done before
    cur = (cur == 2) ? 0 : cur + 1;           // next iter's stage overwrites it
    nxt = (nxt == 2) ? 0 : nxt + 1;
  }
}

// Per-lane staging geometry shared by both GEMMs: lane l of wave w stages the
// 16B chunk ((l&3) ^ ((l>>3)&3)) of row (w*16 + (l>>2)) -- the XOR places
// chunk c of row r in LDS slot c ^ ((r>>1)&3) with a LINEAR LDS destination.
__device__ __forceinline__ int stage_colb(int l) {
  return (((l & 3) ^ ((l >> 3) & 3)) * 16);
}

// ---------------------------------------------------------------------------
// Gating: one wave per token, all f32. scores = sigmoid(x @ Wg^T + bg + bias);
// top-2 with lax.top_k tie-break (lowest index first). Slot via atomics.
// ---------------------------------------------------------------------------
__global__ void __launch_bounds__(64) moe_gate(
    const float* __restrict__ x, const float* __restrict__ Wg,
    const float* __restrict__ bg, const float* __restrict__ bias,
    int* __restrict__ counts, int* __restrict__ topk_idx,
    float* __restrict__ topk_w, int* __restrict__ slot) {
  const int t = blockIdx.x, lane = threadIdx.x;
  float xv[16];
#pragma unroll
  for (int q = 0; q < 16; ++q) xv[q] = x[(size_t)t * DDIM + q * 64 + lane];
  float sc[NEXP];
#pragma unroll
  for (int e = 0; e < NEXP; ++e) {
    float s = 0.f;
#pragma unroll
    for (int q = 0; q < 16; ++q) s += xv[q] * Wg[(size_t)e * DDIM + q * 64 + lane];
#pragma unroll
    for (int o = 32; o > 0; o >>= 1) s += __shfl_xor(s, o, 64);
    sc[e] = 1.0f / (1.0f + expf(-(s + bg[e] + bias[e])));
  }
  if (lane == 0) {
    int k0 = 0;
    for (int e = 1; e < NEXP; ++e)
      if (sc[e] > sc[k0]) k0 = e;
    int k1 = (k0 == 0) ? 1 : 0;
    for (int e = 0; e < NEXP; ++e) {
      if (e == k0) continue;
      if (sc[e] > sc[k1]) k1 = e;
    }
    topk_idx[t * 2 + 0] = k0;
    topk_idx[t * 2 + 1] = k1;
    topk_w[t * 2 + 0] = sc[k0];
    topk_w[t * 2 + 1] = sc[k1];
    slot[t * 2 + 0] = atomicAdd(&counts[k0], 1);
    slot[t * 2 + 1] = atomicAdd(&counts[k1], 1);
  }
}

__global__ void moe_scan(const int* __restrict__ counts, int* __restrict__ offsets) {
  if (threadIdx.x == 0) {
    int s = 0;
    for (int e = 0; e < NEXP; ++e) { offsets[e] = s; s += counts[e]; }
    offsets[NEXP] = s;  // == 2*NTOK
  }
}

__global__ void moe_scatter(const int* __restrict__ topk_idx, const float* __restrict__ topk_w,
                            const int* __restrict__ slot, const int* __restrict__ offsets,
                            int* __restrict__ row_token, float* __restrict__ row_w) {
  const int t = blockIdx.x * blockDim.x + threadIdx.x;
  if (t >= NTOK) return;
#pragma unroll
  for (int k = 0; k < 2; ++k) {
    const int e = topk_idx[t * 2 + k];
    const int rg = offsets[e] + slot[t * 2 + k];
    row_token[rg] = t;
    row_w[rg] = topk_w[t * 2 + k];
  }
  // shared "expert 8": every token, weight 1.0, rows [2*NTOK, 3*NTOK)
  row_token[2 * NTOK + t] = t;
  row_w[2 * NTOK + t] = 1.0f;
}

// ---------------------------------------------------------------------------
// Grouped GEMM1: h1[row,:] = gelu(xbf[token(row),:] @ W1bf[e]^T + b1[e]) (bf16)
// grid (H/128, 16, E+1); e==NEXP -> shared expert (Ws1bf, bs1).
// ---------------------------------------------------------------------------
__global__ void __launch_bounds__(256) moe_gemm1(
    const __hip_bfloat16* __restrict__ xbf, const __hip_bfloat16* __restrict__ W1bf,
    const float* __restrict__ b1, const __hip_bfloat16* __restrict__ Ws1bf,
    const float* __restrict__ bs1, const int* __restrict__ counts,
    const int* __restrict__ offsets, const int* __restrict__ row_token,
    __hip_bfloat16* __restrict__ h1) {
  __shared__ alignas(16) char sm[49152];
  const int e = blockIdx.z, mt = blockIdx.y, nt = blockIdx.x;
  const int cnt = (e < NEXP) ? counts[e] : NTOK;
  if (mt * 128 >= cnt) return;
  const int off = (e < NEXP) ? offsets[e] : 2 * NTOK;
  const __hip_bfloat16* Bw = (e < NEXP) ? (W1bf + (size_t)e * HDIM * DDIM) : Ws1bf;
  const float* bb = (e < NEXP) ? (b1 + e * HDIM) : bs1;

  const int tid = threadIdx.x;
  const int w = tid >> 6, l = tid & 63;
  const int mrow = w * 16 + (l >> 2);   // 0..63 staging row
  const int colb = stage_colb(l);       // swizzled 16B chunk col offset

  const int r0 = mt * 128 + mrow, r1 = r0 + 64;
  const int c0 = (r0 < cnt) ? r0 : (cnt - 1);
  const int c1 = (r1 < cnt) ? r1 : (cnt - 1);
  const int t0 = row_token[off + c0];
  const int t1 = row_token[off + c1];
  const char* ga0 = (const char*)xbf + (size_t)t0 * (DDIM * 2) + colb;
  const char* ga1 = (const char*)xbf + (size_t)t1 * (DDIM * 2) + colb;
  const char* gb0 = (const char*)Bw + (size_t)(nt * 128 + mrow) * (DDIM * 2) + colb;
  const char* gb1 = (const char*)Bw + (size_t)(nt * 128 + mrow + 64) * (DDIM * 2) + colb;

  f32x4 acc[4][4] = {};
  gemm_core(ga0, ga1, gb0, gb1, sm, DDIM * 2, tid, acc);

  const int lr = l & 15, quad = l >> 4, wr = w >> 1, wc = w & 1;
#pragma unroll
  for (int i = 0; i < 4; ++i) {
#pragma unroll
    for (int r = 0; r < 4; ++r) {
      const int rowe = mt * 128 + wr * 64 + i * 16 + quad * 4 + r;
      if (rowe >= cnt) continue;  // don't stomp next expert's rows
      const size_t orow = (size_t)(off + rowe) * HDIM;
#pragma unroll
      for (int j = 0; j < 4; ++j) {
        const int h = nt * 128 + wc * 64 + j * 16 + lr;
        const float v = acc[i][j][r] + bb[h];
        h1[orow + h] = __float2bfloat16(gelu_fast(v));
      }
    }
  }
}

// ---------------------------------------------------------------------------
// Grouped GEMM2 with split-K: out[token,:] += w(row)*(h1[row,:] @ W2bf[e]^T)
// (+ w*b2[e] from K-chunk 0 only). grid x = KSPLIT2 * (D/128); y = m-tiles;
// z = E+1 groups. out is f32, pre-zeroed; f32 atomicAdd accumulates.
// ---------------------------------------------------------------------------
__global__ void __launch_bounds__(256) moe_gemm2(
    const __hip_bfloat16* __restrict__ h1, const __hip_bfloat16* __restrict__ W2bf,
    const float* __restrict__ b2, const __hip_bfloat16* __restrict__ Ws2bf,
    const float* __restrict__ bs2, const int* __restrict__ counts,
    const int* __restrict__ offsets, const int* __restrict__ row_token,
    const float* __restrict__ row_w, float* __restrict__ out) {
  __shared__ alignas(16) char sm[49152];
  const int e = blockIdx.z, mt = blockIdx.y;
  const int nt = blockIdx.x & (DDIM / 128 - 1);
  const int kc = blockIdx.x >> 3;  // K-chunk 0..KSPLIT2-1
  const int cnt = (e < NEXP) ? counts[e] : NTOK;
  if (mt * 128 >= cnt) return;
  const int off = (e < NEXP) ? offsets[e] : 2 * NTOK;
  const __hip_bfloat16* Bw = (e < NEXP) ? (W2bf + (size_t)e * DDIM * HDIM) : Ws2bf;
  const float* bb = (e < NEXP) ? (b2 + e * DDIM) : bs2;

  const int tid = threadIdx.x;
  const int w = tid >> 6, l = tid & 63;
  const int mrow = w * 16 + (l >> 2);
  const int colb = stage_colb(l);            // swizzled 16B chunk col offset
  const int KB = (HDIM * 2) / KSPLIT2;       // bytes of K per chunk
  const size_t kofs = (size_t)kc * KB;       // byte offset into the K dim

  // A rows contiguous in grouped h1; rows >= cnt read the next group's valid
  // (finite) data and are discarded at the store guard.
  const char* ga0 = (const char*)h1 + (size_t)(off + mt * 128 + mrow) * (HDIM * 2) + kofs + colb;
  const char* ga1 = (const char*)h1 + (size_t)(off + mt * 128 + mrow + 64) * (HDIM * 2) + kofs + colb;
  const char* gb0 = (const char*)Bw + (size_t)(nt * 128 + mrow) * (HDIM * 2) + kofs + colb;
  const char* gb1 = (const char*)Bw + (size_t)(nt * 128 + mrow + 64) * (HDIM * 2) + kofs + colb;

  f32x4 acc[4][4] = {};
  gemm_core(ga0, ga1, gb0, gb1, sm, KB, tid, acc);

  const int lr = l & 15, quad = l >> 4, wr = w >> 1, wc = w & 1;
#pragma unroll
  for (int i = 0; i < 4; ++i) {
#pragma unroll
    for (int r = 0; r < 4; ++r) {
      const int rowe = mt * 128 + wr * 64 + i * 16 + quad * 4 + r;
      if (rowe >= cnt) continue;
      const int rg = off + rowe;
      const int tok = row_token[rg];
      const float wt = row_w[rg];
#pragma unroll
      for (int j = 0; j < 4; ++j) {
        const int d = nt * 128 + wc * 64 + j * 16 + lr;
        const float base = (kc == 0) ? bb[d] : 0.f;  // bias once per output
        atomicAdd(&out[(size_t)tok * DDIM + d], wt * (acc[i][j][r] + base));
      }
    }
  }
}

// ---------------------------------------------------------------------------
extern "C" void kernel_launch(void* const* d_in, const int* in_sizes, int n_in,
                              void* d_out, int out_size, void* d_ws, size_t ws_size,
                              hipStream_t stream) {
  (void)in_sizes; (void)n_in; (void)out_size; (void)ws_size;
  const float* x    = (const float*)d_in[0];
  const float* Wg   = (const float*)d_in[1];
  const float* bg   = (const float*)d_in[2];
  const float* bias = (const float*)d_in[3];
  const float* W1   = (const float*)d_in[4];
  const float* b1   = (const float*)d_in[5];
  const float* W2   = (const float*)d_in[6];
  const float* b2   = (const float*)d_in[7];
  const float* Ws1  = (const float*)d_in[8];
  const float* bs1  = (const float*)d_in[9];
  const float* Ws2  = (const float*)d_in[10];
  const float* bs2  = (const float*)d_in[11];
  float* out = (float*)d_out;

  // workspace carve-out (~200 MB)
  char* ws = (char*)d_ws;
  size_t cur = 0;
  auto take = [&](size_t b) -> void* {
    void* p = ws + cur;
    cur += (b + 255) & ~(size_t)255;
    return p;
  };
  int* counts    = (int*)take(NEXP * 4);
  int* offsets   = (int*)take((NEXP + 1) * 4);
  int* topk_idx  = (int*)take(NTOK * 2 * 4);
  float* topk_w  = (float*)take(NTOK * 2 * 4);
  int* slot      = (int*)take(NTOK * 2 * 4);
  int* row_token = (int*)take(NROWS * 4);
  float* row_w   = (float*)take(NROWS * 4);
  __hip_bfloat16* xbf   = (__hip_bfloat16*)take((size_t)NTOK * DDIM * 2);        //  4 MB
  __hip_bfloat16* W1bf  = (__hip_bfloat16*)take((size_t)NEXP * HDIM * DDIM * 2); // 67 MB
  __hip_bfloat16* W2bf  = (__hip_bfloat16*)take((size_t)NEXP * DDIM * HDIM * 2); // 67 MB
  __hip_bfloat16* Ws1bf = (__hip_bfloat16*)take((size_t)HDIM * DDIM * 2);        //  8 MB
  __hip_bfloat16* Ws2bf = (__hip_bfloat16*)take((size_t)DDIM * HDIM * 2);        //  8 MB
  __hip_bfloat16* h1    = (__hip_bfloat16*)take((size_t)(NROWS + 64) * HDIM * 2);// 51 MB

  // f32 -> bf16 conversions (all sizes divisible by 2048)
  cvt_bf16<<<(NTOK * DDIM) / 2048, 256, 0, stream>>>(x, xbf);
  cvt_bf16<<<(NEXP * HDIM * DDIM) / 2048, 256, 0, stream>>>(W1, W1bf);
  cvt_bf16<<<(NEXP * DDIM * HDIM) / 2048, 256, 0, stream>>>(W2, W2bf);
  cvt_bf16<<<(HDIM * DDIM) / 2048, 256, 0, stream>>>(Ws1, Ws1bf);
  cvt_bf16<<<(DDIM * HDIM) / 2048, 256, 0, stream>>>(Ws2, Ws2bf);

  moe_zero_misc<<<1, 64, 0, stream>>>(counts);
  moe_zero_out<<<(NTOK * DDIM) / 256, 256, 0, stream>>>(out);
  moe_gate<<<NTOK, 64, 0, stream>>>(x, Wg, bg, bias, counts, topk_idx, topk_w, slot);
  moe_scan<<<1, 1, 0, stream>>>(counts, offsets);
  moe_scatter<<<NTOK / 256, 256, 0, stream>>>(topk_idx, topk_w, slot, offsets, row_token, row_w);

  dim3 g1(HDIM / 128, NTOK / 128, NEXP + 1);  // (32, 16, 9), early-exit past counts
  moe_gemm1<<<g1, 256, 0, stream>>>(xbf, W1bf, b1, Ws1bf, bs1, counts, offsets, row_token, h1);

  dim3 g2(KSPLIT2 * (DDIM / 128), NTOK / 128, NEXP + 1);  // (16, 16, 9), split-K
  moe_gemm2<<<g2, 256, 0, stream>>>(h1, W2bf, b2, Ws2bf, bs2, counts, offsets, row_token, row_w, out);
}